// Round 1
// baseline (228.257 us; speedup 1.0000x reference)
//
#include <hip/hip_runtime.h>

// Integrate-and-fire scan: x_seq (T=64, 128, 4096) f32 -> s_seq same shape.
//   v += x[t]; s = (v >= 1.0f); v -= s;
// Streaming, memory-bound. Ideal traffic 268 MB -> ~42 us at 6.3-6.7 TB/s.
//
// Round-2 theory: the 226 us plateau (both with and without load pipelining)
// is the __builtin_nontemporal_store path. NT stores bypass L2 write-combining
// (the harness fill kernel proves CACHED stores reach 6.69 TB/s) and retire at
// memory-ack in the in-order vmcnt queue, so every load wait transitively
// waits on slow store retirement. NT buys nothing here: output streams through
// L2 once, input is read-once (no reuse to protect).
// Change: plain stores + float4 (16 B/lane sweet spot, halves VMEM instrs).
// Keep the proven issue-ahead register double-buffer.

#define TSTEPS 64
#define NCOLS  (128 * 4096)    // 524288 columns
#define NCOLS4 (NCOLS / 4)     // 131072 float4 column-groups, 2 MiB time stride
#define BATCH  4               // float4 loads in flight per wave (64 B/lane)

__global__ __launch_bounds__(256) void TandemIF_86096914416163_kernel(
    const float4* __restrict__ x, float4* __restrict__ out)
{
    const int c = blockIdx.x * 256 + threadIdx.x;   // grid sized exactly
    const float4* xp = x   + c;
    float4*       op = out + c;

    float vx = 0.0f, vy = 0.0f, vz = 0.0f, vw = 0.0f;
    float4 buf[2][BATCH];

    // Prime the pipeline: batch 0 in flight.
#pragma unroll
    for (int j = 0; j < BATCH; ++j)
        buf[0][j] = xp[j * NCOLS4];

    // Fully unrolled outer loop -> buffers stay in registers, ping-pong static.
#pragma unroll
    for (int tb = 0; tb < TSTEPS / BATCH; ++tb) {
        const int cur = tb & 1, nxt = cur ^ 1;

        // Issue next batch's loads BEFORE consuming current batch: vmcnt
        // retires in order, these sit BEHIND the current batch in the queue,
        // so waiting on cur[j] never waits on them.
        if (tb < TSTEPS / BATCH - 1) {
#pragma unroll
            for (int j = 0; j < BATCH; ++j)
                buf[nxt][j] = xp[((tb + 1) * BATCH + j) * NCOLS4];
        }

#pragma unroll
        for (int j = 0; j < BATCH; ++j) {
            const float4 xt = buf[cur][j];
            vx += xt.x; vy += xt.y; vz += xt.z; vw += xt.w;
            const float sx = (vx >= 1.0f) ? 1.0f : 0.0f;
            const float sy = (vy >= 1.0f) ? 1.0f : 0.0f;
            const float sz = (vz >= 1.0f) ? 1.0f : 0.0f;
            const float sw = (vw >= 1.0f) ? 1.0f : 0.0f;
            vx -= sx; vy -= sy; vz -= sz; vw -= sw;
            // Plain cached store: full 64B lines per wave (1 KB contiguous),
            // L2 write-combines and writes back at the fill-kernel rate.
            op[(tb * BATCH + j) * NCOLS4] = make_float4(sx, sy, sz, sw);
        }
    }
}

extern "C" void kernel_launch(void* const* d_in, const int* in_sizes, int n_in,
                              void* d_out, int out_size, void* d_ws, size_t ws_size,
                              hipStream_t stream)
{
    const float4* x = (const float4*)d_in[0];
    float4* out     = (float4*)d_out;
    // 131072 float4 columns / 256 threads = 512 blocks (2 blocks/CU, 8 waves/CU)
    TandemIF_86096914416163_kernel<<<dim3(NCOLS4 / 256), dim3(256), 0, stream>>>(x, out);
}